// Round 5
// baseline (3404.279 us; speedup 1.0000x reference)
//
#include <hip/hip_runtime.h>
#include <cstdint>
#include <cstddef>

#define N_NODES 5000
#define F_IN    7699
#define KP1     7712   // F_IN padded to mult of 32
#define KT1     241    // KP1/32
#define MP      5120   // rows padded to mult of 128
#define E_EDGES 40000
#define EFULL   45000  // E + N self loops
#define HC1     4096   // heads1*ch1
#define N1      8192   // xl|xr concat
#define HC2     1024
#define N2      2048
#define NOUT    128

typedef __bf16 bf16x8 __attribute__((ext_vector_type(8)));
typedef float  f32x4  __attribute__((ext_vector_type(4)));
typedef unsigned int u32x4 __attribute__((ext_vector_type(4)));
typedef unsigned short u16x8 __attribute__((ext_vector_type(8)));

using as1_uchar = unsigned char __attribute__((address_space(1)));
using as3_uchar = unsigned char __attribute__((address_space(3)));

__device__ __forceinline__ unsigned short f2bf(float f) {
  union { float f; unsigned int u; } v; v.f = f;
  return (unsigned short)((v.u + 0x7fffu + ((v.u >> 16) & 1u)) >> 16);
}
__device__ __forceinline__ float bf2f(unsigned short h) {
  union { unsigned int u; float f; } v; v.u = ((unsigned int)h) << 16;
  return v.f;
}

__device__ __forceinline__ void gload16(const void* g, void* l) {
  __builtin_amdgcn_global_load_lds(
      reinterpret_cast<const as1_uchar*>(reinterpret_cast<uintptr_t>(g)),
      reinterpret_cast<as3_uchar*>(reinterpret_cast<uintptr_t>(l)),
      16, 0, 0);
}

// Brick layout for GEMM-A operands (global, matches LDS chunk-plane exactly):
// element (row r, k c) -> ((r>>7)*KT + (c>>5))*4096 + ((c>>3)&3)*1024 + (r&127)*8 + (c&7)

// ---------------- conversion: x -> hi/lo bricks ----------------

__global__ void k_split_x(const float* __restrict__ x, unsigned short* __restrict__ hi,
                          unsigned short* __restrict__ lo) {
  const int C8 = KP1 / 8;                       // 964
  int ci = blockIdx.x * 256 + threadIdx.x;
  if (ci >= MP * C8) return;
  int r = ci / C8, c8 = ci % C8;
  int c = c8 * 8;
  u16x8 hb, lb;
  #pragma unroll
  for (int j = 0; j < 8; ++j) {
    float v = 0.f;
    if (r < N_NODES && (c + j) < F_IN) v = x[(size_t)r * F_IN + c + j];
    unsigned short h = f2bf(v);
    hb[j] = h; lb[j] = f2bf(v - bf2f(h));
  }
  size_t off = ((size_t)((r >> 7) * KT1 + (c >> 5)) * 4 + ((c >> 3) & 3)) * 1024 + (r & 127) * 8;
  *(u16x8*)&hi[off] = hb;
  *(u16x8*)&lo[off] = lb;
}

// ---------------- split-bf16 GEMM, brick-A, streamed-B, pipelined dbuf ----------------
// 128x128 tile, BK=32, 4 waves 2x2, 48 MFMA/wave/K-step.
// Double-buffered LDS (64KB); counted s_waitcnt vmcnt(16) keeps the 16 B-prefetch
// loads in flight across the barrier (T3/T4); one barrier per K-step.

__global__ __launch_bounds__(256, 2) void k_gemm_bs(
    const unsigned short* __restrict__ Ahi, const unsigned short* __restrict__ Alo,
    const float* __restrict__ B0, const float* __restrict__ B1, int ldB, int halfNB,
    float* __restrict__ C, const float* __restrict__ bias0, const float* __restrict__ bias1,
    int halfN, int M, int ldC, int KT, int Klim, int gm, const float* __restrict__ zbuf)
{
  __shared__ __align__(16) unsigned short AhS[2 * 4096];
  __shared__ __align__(16) unsigned short AlS[2 * 4096];
  __shared__ __align__(16) unsigned short BhS[2 * 4096];
  __shared__ __align__(16) unsigned short BlS[2 * 4096];

  const int tid = threadIdx.x;
  const int lane = tid & 63;
  const int w = tid >> 6;
  const int wm = w >> 1, wn = w & 1;

  // bijective XCD swizzle; column-major (consecutive blocks share the B panel)
  const int chunkg = gridDim.x >> 3;
  const int wg = (blockIdx.x & 7) * chunkg + (blockIdx.x >> 3);
  const int bm = wg % gm, bn = wg / gm;

  const float* Bp = (bn < halfNB) ? B0 : B1;
  const int cb = ((bn < halfNB) ? bn : bn - halfNB) * 128;

  f32x4 acc[4][4] = {};

  const unsigned short* AbH = Ahi + (size_t)bm * KT * 4096;
  const unsigned short* AbL = Alo + (size_t)bm * KT * 4096;
  const int sOff = w * 1024 + lane * 8;   // ushort offset of this lane within brick

  const int ccB = tid & 127;              // B column owned by this thread
  const int kB0 = (tid >> 7) * 16;        // B k sub-range base
  const int c0  = (tid >> 7) * 2;         // first chunk-plane for B write

  const int fr = lane & 15;
  const int fchunk = (lane >> 4) * 1024;

  float breg[16];

  auto loadB = [&](int kt) {
    #pragma unroll
    for (int j = 0; j < 16; ++j) {
      int kg = kt * 32 + kB0 + j;
      // ALWAYS issue exactly 16 loads (uniform vmcnt across waves/iterations)
      const float* sp = (kg < Klim) ? (Bp + (size_t)kg * ldB + cb + ccB) : (zbuf + ccB);
      breg[j] = *sp;
    }
  };
  auto stageA = [&](int kt, int p) {
    const unsigned short* bh = AbH + (size_t)kt * 4096 + sOff;
    const unsigned short* bl = AbL + (size_t)kt * 4096 + sOff;
    gload16(bh,       &AhS[p * 4096 + w * 1024]);
    gload16(bh + 512, &AhS[p * 4096 + w * 1024 + 512]);
    gload16(bl,       &AlS[p * 4096 + w * 1024]);
    gload16(bl + 512, &AlS[p * 4096 + w * 1024 + 512]);
  };
  auto convB = [&](int p) {
    #pragma unroll
    for (int u = 0; u < 2; ++u) {
      u32x4 hv, lv;
      #pragma unroll
      for (int m = 0; m < 4; ++m) {
        float a0f = breg[8 * u + 2 * m], a1f = breg[8 * u + 2 * m + 1];
        unsigned int ph, pl;
        asm("v_cvt_pk_bf16_f32 %0, %1, %2" : "=v"(ph) : "v"(a0f), "v"(a1f));
        union { unsigned int u_; float f; } h0, h1;
        h0.u_ = ph << 16; h1.u_ = ph & 0xFFFF0000u;
        float l0 = a0f - h0.f, l1 = a1f - h1.f;
        asm("v_cvt_pk_bf16_f32 %0, %1, %2" : "=v"(pl) : "v"(l0), "v"(l1));
        hv[m] = ph; lv[m] = pl;
      }
      const int off = p * 4096 + (c0 + u) * 1024 + ccB * 8;
      *(u32x4*)&BhS[off] = hv;
      *(u32x4*)&BlS[off] = lv;
    }
  };

  // ---- prologue: buf0 = tile0; breg = tile1; 16 loads in flight ----
  loadB(0);
  stageA(0, 0);
  convB(0);            // compiler waits the 16 loadB(0) loads (vmcnt(4))
  loadB(1);
  asm volatile("s_waitcnt vmcnt(16) lgkmcnt(0)" ::: "memory");  // drain 4 stageA gloads
  __builtin_amdgcn_s_barrier();
  __builtin_amdgcn_sched_barrier(0);

  int p = 0;
  for (int kt = 0; kt < KT; ++kt) {
    // issue next tile's staging FIRST (hides under MFMA below)
    const int ktn = (kt + 1 < KT) ? kt + 1 : kt;   // clamped re-stage at tail (unused)
    stageA(ktn, p ^ 1);
    convB(p ^ 1);          // breg holds tile kt+1 (zeros at tail)
    loadB(kt + 2);         // OOB -> zbuf; always 16 loads

    // compute tile kt from buf[p]
    bf16x8 ah[4], al[4];
    #pragma unroll
    for (int i = 0; i < 4; ++i) {
      const int ro = p * 4096 + fchunk + (wm * 64 + i * 16 + fr) * 8;
      ah[i] = *(const bf16x8*)&AhS[ro];
      al[i] = *(const bf16x8*)&AlS[ro];
    }
    __builtin_amdgcn_s_setprio(1);
    #pragma unroll
    for (int j = 0; j < 4; ++j) {
      const int ro = p * 4096 + fchunk + (wn * 64 + j * 16 + fr) * 8;
      bf16x8 bh = *(const bf16x8*)&BhS[ro];
      bf16x8 bl = *(const bf16x8*)&BlS[ro];
      #pragma unroll
      for (int i = 0; i < 4; ++i) {
        acc[i][j] = __builtin_amdgcn_mfma_f32_16x16x32_bf16(ah[i], bh, acc[i][j], 0, 0, 0);
        acc[i][j] = __builtin_amdgcn_mfma_f32_16x16x32_bf16(al[i], bh, acc[i][j], 0, 0, 0);
        acc[i][j] = __builtin_amdgcn_mfma_f32_16x16x32_bf16(ah[i], bl, acc[i][j], 0, 0, 0);
      }
    }
    __builtin_amdgcn_s_setprio(0);

    // counted wait: drain the 4 stageA gloads (oldest), keep 16 breg loads in flight
    asm volatile("s_waitcnt vmcnt(16) lgkmcnt(0)" ::: "memory");
    __builtin_amdgcn_s_barrier();
    __builtin_amdgcn_sched_barrier(0);
    p ^= 1;
  }

  // epilogue: C/D layout col=lane&15, row=(lane>>4)*4+reg
  const int rowb = bm * 128 + wm * 64 + (lane >> 4) * 4;
  const int colb = bn * 128 + wn * 64 + (lane & 15);
  #pragma unroll
  for (int i = 0; i < 4; ++i) {
    #pragma unroll
    for (int j = 0; j < 4; ++j) {
      int gc = colb + j * 16;
      float bvv = (gc < halfN) ? bias0[gc] : bias1[gc - halfN];
      #pragma unroll
      for (int r = 0; r < 4; ++r) {
        int gr = rowb + i * 16 + r;
        if (gr < M) C[(size_t)gr * ldC + gc] = acc[i][j][r] + bvv;
      }
    }
  }
}

// ---------------- graph prep ----------------

__global__ void k_deg(const int* __restrict__ dst, const float* __restrict__ ea,
                      float* __restrict__ deg, float* __restrict__ lattr, int E) {
  int e = blockIdx.x * 256 + threadIdx.x;
  if (e >= E) return;
  int d = dst[e];
  atomicAdd(&deg[d], 1.f);
  atomicAdd(&lattr[d * 3 + 0], ea[e * 3 + 0]);
  atomicAdd(&lattr[d * 3 + 1], ea[e * 3 + 1]);
  atomicAdd(&lattr[d * 3 + 2], ea[e * 3 + 2]);
}

__global__ void k_lattr_fin(float* __restrict__ lattr, const float* __restrict__ deg, int n) {
  int i = blockIdx.x * 256 + threadIdx.x;
  if (i >= n) return;
  float dv = fmaxf(deg[i], 1.f);
  lattr[i * 3 + 0] /= dv; lattr[i * 3 + 1] /= dv; lattr[i * 3 + 2] /= dv;
}

__global__ void k_eafull(const float* __restrict__ ea, const float* __restrict__ lattr,
                         float* __restrict__ eaf, int E, int n) {
  int e = blockIdx.x * 256 + threadIdx.x;
  if (e >= E + n) return;
  const float* s = (e < E) ? &ea[(size_t)e * 3] : &lattr[(size_t)(e - E) * 3];
  eaf[e * 3 + 0] = s[0]; eaf[e * 3 + 1] = s[1]; eaf[e * 3 + 2] = s[2];
}

__global__ void k_count(const int* __restrict__ dst, int* __restrict__ cnt, int E, int n) {
  int e = blockIdx.x * 256 + threadIdx.x;
  if (e >= E + n) return;
  int d = (e < E) ? dst[e] : (e - E);
  atomicAdd(&cnt[d], 1);
}

__global__ void k_scan(const int* __restrict__ cnt, int* __restrict__ rowptr, int n) {
  int lane = threadIdx.x;   // 64 threads, 1 block
  int run = 0;
  for (int base = 0; base < n; base += 64) {
    int i = base + lane;
    int v = (i < n) ? cnt[i] : 0;
    #pragma unroll
    for (int off = 1; off < 64; off <<= 1) {
      int t = __shfl_up(v, off, 64);
      if (lane >= off) v += t;
    }
    if (i < n) rowptr[i + 1] = run + v;
    run += __shfl(v, 63, 64);
  }
  if (lane == 0) rowptr[0] = 0;
}

__global__ void k_fill(const int* __restrict__ dst, const int* __restrict__ rowptr,
                       int* __restrict__ fillc, int* __restrict__ elist, int E, int n) {
  int e = blockIdx.x * 256 + threadIdx.x;
  if (e >= E + n) return;
  int d = (e < E) ? dst[e] : (e - E);
  int pos = rowptr[d] + atomicAdd(&fillc[d], 1);
  elist[pos] = e;
}

// ---------------- GATv2 edge phase (f32) ----------------

template <int H, int ITERS>
__global__ __launch_bounds__(256) void k_logit(
    const float* __restrict__ xl, const float* __restrict__ xr, int strideX,
    const float* __restrict__ eaf, const float* __restrict__ We, const float* __restrict__ att,
    const int* __restrict__ src, const int* __restrict__ dst, int E,
    float* __restrict__ logit)
{
  const int e = blockIdx.x;
  const int tid = threadIdx.x;
  int s, d;
  if (e < E) { s = src[e]; d = dst[e]; } else { s = e - E; d = s; }
  const float ea0 = eaf[e * 3 + 0], ea1 = eaf[e * 3 + 1], ea2 = eaf[e * 3 + 2];
  constexpr int HC = ITERS * 256;
  const float* rl = xl + (size_t)s * strideX;
  const float* rr = xr + (size_t)d * strideX;
  float acc[H];
  #pragma unroll
  for (int h = 0; h < H; ++h) acc[h] = 0.f;
  #pragma unroll
  for (int i = 0; i < ITERS; ++i) {
    int hc = tid + (i << 8);
    float v = rl[hc] + rr[hc] + ea0 * We[hc] + ea1 * We[HC + hc] + ea2 * We[2 * HC + hc];
    v = (v > 0.f) ? v : 0.2f * v;
    acc[i >> 2] += v * att[hc];
  }
  __shared__ float red[H][4];
  const int lane = tid & 63, wv = tid >> 6;
  #pragma unroll
  for (int h = 0; h < H; ++h) {
    float v = acc[h];
    #pragma unroll
    for (int off = 32; off > 0; off >>= 1) v += __shfl_down(v, off, 64);
    if (lane == 0) red[h][wv] = v;
  }
  __syncthreads();
  if (tid < H)
    logit[(size_t)e * H + tid] = red[tid][0] + red[tid][1] + red[tid][2] + red[tid][3];
}

template <int H>
__global__ void k_stats(const float* __restrict__ logit, const int* __restrict__ rowptr,
                        const int* __restrict__ elist, float* __restrict__ mb, float* __restrict__ db)
{
  const int n = blockIdx.x;
  const int lane = threadIdx.x;   // 64
  const int start = rowptr[n], end = rowptr[n + 1];
  #pragma unroll
  for (int h = 0; h < H; ++h) {
    float m = -1e30f;
    for (int p = start + lane; p < end; p += 64)
      m = fmaxf(m, logit[(size_t)elist[p] * H + h]);
    #pragma unroll
    for (int off = 32; off > 0; off >>= 1) m = fmaxf(m, __shfl_down(m, off, 64));
    m = __shfl(m, 0, 64);
    float sum = 0.f;
    for (int p = start + lane; p < end; p += 64)
      sum += __expf(logit[(size_t)elist[p] * H + h] - m);
    #pragma unroll
    for (int off = 32; off > 0; off >>= 1) sum += __shfl_down(sum, off, 64);
    if (lane == 0) { mb[n * H + h] = m; db[n * H + h] = sum; }
  }
}

// out[n][hc] = sum_e alpha*xl[src][hc] + bias, stored as hi/lo BRICKS (GEMM-A layout).
template <int H, int NC8, int KTo>
__global__ __launch_bounds__(256) void k_agg(
    const float* __restrict__ xl, int strideX,
    const int* __restrict__ rowptr, const int* __restrict__ elist, const int* __restrict__ src,
    const float* __restrict__ logit, const float* __restrict__ mb, const float* __restrict__ db,
    const float* __restrict__ bias,
    unsigned short* __restrict__ ohi, unsigned short* __restrict__ olo, int E)
{
  const int n = blockIdx.x;
  const int tid = threadIdx.x;
  constexpr int HC = H * 1024;
  float acc[NC8][8];
  #pragma unroll
  for (int q = 0; q < NC8; ++q)
    #pragma unroll
    for (int j = 0; j < 8; ++j) acc[q][j] = 0.f;
  const int start = rowptr[n], end = rowptr[n + 1];
  float mloc[H], dloc[H];
  #pragma unroll
  for (int h = 0; h < H; ++h) { mloc[h] = mb[n * H + h]; dloc[h] = db[n * H + h] + 1e-16f; }
  for (int p = start; p < end; ++p) {
    const int e = elist[p];
    const int s = (e < E) ? src[e] : (e - E);
    float al[H];
    #pragma unroll
    for (int h = 0; h < H; ++h)
      al[h] = __expf(logit[(size_t)e * H + h] - mloc[h]) / dloc[h];
    const float* row = xl + (size_t)s * strideX;
    #pragma unroll
    for (int q = 0; q < NC8; ++q) {
      const int c8 = tid + q * 256;
      if (c8 * 8 < HC) {
        float a = (H == 4) ? ((tid & 128) ? al[2 * q + 1] : al[2 * q]) : al[0];
        f32x4 v0 = *(const f32x4*)(row + c8 * 8);
        f32x4 v1 = *(const f32x4*)(row + c8 * 8 + 4);
        #pragma unroll
        for (int j = 0; j < 4; ++j) { acc[q][j] += a * v0[j]; acc[q][4 + j] += a * v1[j]; }
      }
    }
  }
  #pragma unroll
  for (int q = 0; q < NC8; ++q) {
    const int c8 = tid + q * 256;
    if (c8 * 8 < HC) {
      u16x8 hb, lb;
      #pragma unroll
      for (int j = 0; j < 8; ++j) {
        float v = acc[q][j] + bias[c8 * 8 + j];
        unsigned short h = f2bf(v);
        hb[j] = h; lb[j] = f2bf(v - bf2f(h));
      }
      size_t off = ((size_t)((n >> 7) * KTo + (c8 >> 2)) * 4 + (c8 & 3)) * 1024 + (n & 127) * 8;
      *(u16x8*)&ohi[off] = hb;
      *(u16x8*)&olo[off] = lb;
    }
  }
}

// ---------------- launch ----------------

extern "C" void kernel_launch(void* const* d_in, const int* in_sizes, int n_in,
                              void* d_out, int out_size, void* d_ws, size_t ws_size,
                              hipStream_t stream) {
  const float* x    = (const float*)d_in[0];
  const int*   eidx = (const int*)d_in[1];
  const float* eattr= (const float*)d_in[2];
  const float* W1l  = (const float*)d_in[3];
  const float* b1l  = (const float*)d_in[4];
  const float* W1r  = (const float*)d_in[5];
  const float* b1r  = (const float*)d_in[6];
  const float* W1e  = (const float*)d_in[7];
  const float* att1 = (const float*)d_in[8];
  const float* bias1= (const float*)d_in[9];
  const float* W2l  = (const float*)d_in[10];
  const float* b2l  = (const float*)d_in[11];
  const float* W2r  = (const float*)d_in[12];
  const float* b2r  = (const float*)d_in[13];
  const float* W2e  = (const float*)d_in[14];
  const float* att2 = (const float*)d_in[15];
  const float* bias2= (const float*)d_in[16];
  const float* Wlin = (const float*)d_in[17];
  const float* blin = (const float*)d_in[18];
  float* out = (float*)d_out;

  char* ws = (char*)d_ws;
  const int* srcp = eidx;
  const int* dstp = eidx + E_EDGES;

  auto alignup = [](size_t v) { return (v + 255) & ~(size_t)255; };

  // ---- layout (~325 MB) ----
  const size_t oXHI = 0;                                  // 79 MB (bricks)
  const size_t oXLO = oXHI + (size_t)MP * KP1 * 2;        // 79 MB
  const size_t oXLR = oXLO + (size_t)MP * KP1 * 2;        // xl|xr f32 [5000][8192]: 164 MB
  const size_t oS   = oXLR + (size_t)N_NODES * N1 * 4;
  const size_t oLATTR = alignup(oS);
  const size_t oDEG   = alignup(oLATTR + (size_t)N_NODES * 3 * 4);
  const size_t oEAF   = alignup(oDEG + (size_t)N_NODES * 4);
  const size_t oCNT   = alignup(oEAF + (size_t)EFULL * 3 * 4);
  const size_t oROW   = alignup(oCNT + (size_t)N_NODES * 4);
  const size_t oFILL  = alignup(oROW + (size_t)(N_NODES + 1) * 4);
  const size_t oELIST = alignup(oFILL + (size_t)N_NODES * 4);
  const size_t oLOGIT = alignup(oELIST + (size_t)EFULL * 4);
  const size_t oMB    = alignup(oLOGIT + (size_t)EFULL * 4 * 4);
  const size_t oDB    = alignup(oMB + (size_t)N_NODES * 4 * 4);
  const size_t oZBUF  = alignup(oDB + (size_t)N_NODES * 4 * 4);
  const size_t oEND   = alignup(oZBUF + 512);
  if (ws_size < oEND) return;

  // overlays
  const size_t oH1HI = oXHI;                           // bricks [MP][4096]: 42 MB (in 79)
  const size_t oH1LO = oXLO;                           // 42 MB (in 79)
  const size_t oXLR2 = oXLR;                           // f32 [5000][2048]: 41 MB (in 164)
  const size_t oH2HI = oXLR + 64ull * 1024 * 1024;     // bricks [MP][1024]: 10.5 MB
  const size_t oH2LO = oXLR + 80ull * 1024 * 1024;     // 10.5 MB

  unsigned short* XHI  = (unsigned short*)(ws + oXHI);
  unsigned short* XLO  = (unsigned short*)(ws + oXLO);
  float*          XLR  = (float*)(ws + oXLR);
  float*          LATTR= (float*)(ws + oLATTR);
  float*          DEG  = (float*)(ws + oDEG);
  float*          EAF  = (float*)(ws + oEAF);
  int*            CNT  = (int*)(ws + oCNT);
  int*            ROWP = (int*)(ws + oROW);
  int*            FILLC= (int*)(ws + oFILL);
  int*            ELIST= (int*)(ws + oELIST);
  float*          LOGIT= (float*)(ws + oLOGIT);
  float*          MB   = (float*)(ws + oMB);
  float*          DB   = (float*)(ws + oDB);
  float*          ZBUF = (float*)(ws + oZBUF);
  unsigned short* H1HI = (unsigned short*)(ws + oH1HI);
  unsigned short* H1LO = (unsigned short*)(ws + oH1LO);
  float*          XLR2 = (float*)(ws + oXLR2);
  unsigned short* H2HI = (unsigned short*)(ws + oH2HI);
  unsigned short* H2LO = (unsigned short*)(ws + oH2LO);

  hipMemsetAsync(ws + oDEG,   0, (size_t)N_NODES * 4, stream);
  hipMemsetAsync(ws + oLATTR, 0, (size_t)N_NODES * 3 * 4, stream);
  hipMemsetAsync(ws + oCNT,   0, (size_t)N_NODES * 4, stream);
  hipMemsetAsync(ws + oFILL,  0, (size_t)N_NODES * 4, stream);
  hipMemsetAsync(ws + oZBUF,  0, 512, stream);

  const int gE  = (E_EDGES + 255) / 256;
  const int gEF = (EFULL + 255) / 256;
  const int gN  = (N_NODES + 255) / 256;

  // ---- graph structure ----
  k_deg<<<gE, 256, 0, stream>>>(dstp, eattr, DEG, LATTR, E_EDGES);
  k_lattr_fin<<<gN, 256, 0, stream>>>(LATTR, DEG, N_NODES);
  k_eafull<<<gEF, 256, 0, stream>>>(eattr, LATTR, EAF, E_EDGES, N_NODES);
  k_count<<<gEF, 256, 0, stream>>>(dstp, CNT, E_EDGES, N_NODES);
  k_scan<<<1, 64, 0, stream>>>(CNT, ROWP, N_NODES);
  k_fill<<<gEF, 256, 0, stream>>>(dstp, ROWP, FILLC, ELIST, E_EDGES, N_NODES);

  // ---- layer 1 ----
  k_split_x<<<MP * (KP1 / 8) / 256, 256, 0, stream>>>(x, XHI, XLO);
  k_gemm_bs<<<64 * (MP / 128), 256, 0, stream>>>(
      XHI, XLO, W1l, W1r, HC1, 32,
      XLR, b1l, b1r, HC1, N_NODES, N1, KT1, F_IN, MP / 128, ZBUF);

  k_logit<4, 16><<<EFULL, 256, 0, stream>>>(XLR, XLR + HC1, N1, EAF, W1e, att1, srcp, dstp, E_EDGES, LOGIT);
  k_stats<4><<<N_NODES, 64, 0, stream>>>(LOGIT, ROWP, ELIST, MB, DB);
  // zero H1 bricks (pad rows 5000..5119 must be 0 for GEMM2)
  hipMemsetAsync(ws + oH1HI, 0, (size_t)MP * HC1 * 2, stream);
  hipMemsetAsync(ws + oH1LO, 0, (size_t)MP * HC1 * 2, stream);
  k_agg<4, 2, HC1 / 32><<<N_NODES, 256, 0, stream>>>(
      XLR, N1, ROWP, ELIST, srcp, LOGIT, MB, DB, bias1, H1HI, H1LO, E_EDGES);

  // ---- layer 2 ----
  k_gemm_bs<<<16 * (MP / 128), 256, 0, stream>>>(
      H1HI, H1LO, W2l, W2r, HC2, 8,
      XLR2, b2l, b2r, HC2, N_NODES, N2, HC1 / 32, HC1, MP / 128, ZBUF);

  k_logit<1, 4><<<EFULL, 256, 0, stream>>>(XLR2, XLR2 + HC2, N2, EAF, W2e, att2, srcp, dstp, E_EDGES, LOGIT);
  k_stats<1><<<N_NODES, 64, 0, stream>>>(LOGIT, ROWP, ELIST, MB, DB);
  hipMemsetAsync(ws + oH2HI, 0, (size_t)MP * HC2 * 2, stream);
  hipMemsetAsync(ws + oH2LO, 0, (size_t)MP * HC2 * 2, stream);
  k_agg<1, 1, HC2 / 32><<<N_NODES, 256, 0, stream>>>(
      XLR2, N2, ROWP, ELIST, srcp, LOGIT, MB, DB, bias2, H2HI, H2LO, E_EDGES);

  // ---- final linear ----
  k_gemm_bs<<<1 * (MP / 128), 256, 0, stream>>>(
      H2HI, H2LO, Wlin, Wlin, NOUT, 1,
      out, blin, blin, NOUT, N_NODES, NOUT, HC2 / 32, HC2, MP / 128, ZBUF);
}

// Round 6
// 2996.943 us; speedup vs baseline: 1.1359x; 1.1359x over previous
//
#include <hip/hip_runtime.h>
#include <cstdint>
#include <cstddef>

#define N_NODES 5000
#define F_IN    7699
#define KP1     7712   // F_IN padded to mult of 32
#define KT1     241    // KP1/32
#define MP      5120   // rows padded to mult of 128
#define E_EDGES 40000
#define EFULL   45000  // E + N self loops
#define HC1     4096   // heads1*ch1
#define N1      8192   // xl|xr concat
#define HC2     1024
#define N2      2048
#define NOUT    128

typedef __bf16 bf16x8 __attribute__((ext_vector_type(8)));
typedef float  f32x4  __attribute__((ext_vector_type(4)));
typedef float  f32x16 __attribute__((ext_vector_type(16)));
typedef unsigned short u16x8 __attribute__((ext_vector_type(8)));
typedef _Float16 f16;
typedef _Float16 f16x8 __attribute__((ext_vector_type(8)));

using as1_uchar = unsigned char __attribute__((address_space(1)));
using as3_uchar = unsigned char __attribute__((address_space(3)));

__device__ __forceinline__ unsigned short f2bf(float f) {
  union { float f; unsigned int u; } v; v.f = f;
  return (unsigned short)((v.u + 0x7fffu + ((v.u >> 16) & 1u)) >> 16);
}
__device__ __forceinline__ float bf2f(unsigned short h) {
  union { unsigned int u; float f; } v; v.u = ((unsigned int)h) << 16;
  return v.f;
}

__device__ __forceinline__ void gload16(const void* g, void* l) {
  __builtin_amdgcn_global_load_lds(
      reinterpret_cast<const as1_uchar*>(reinterpret_cast<uintptr_t>(g)),
      reinterpret_cast<as3_uchar*>(reinterpret_cast<uintptr_t>(l)),
      16, 0, 0);
}

// Brick layout (global == LDS chunk-plane, zero conflicts):
// element (row r, k c) -> ((r>>7)*KT + (c>>5))*4096 + (((c>>3)&3))*1024 + (r&127)*8 + (c&7)
// one (row-tile, k-step) brick = 8KB, staged as contiguous 1KB gload_lds per wave-half.

// ---------------- x -> hi/lo A-bricks ----------------

__global__ void k_split_x(const float* __restrict__ x, unsigned short* __restrict__ hi,
                          unsigned short* __restrict__ lo) {
  const int C8 = KP1 / 8;                       // 964
  int ci = blockIdx.x * 256 + threadIdx.x;
  if (ci >= MP * C8) return;
  int r = ci / C8, c8 = ci % C8;
  int c = c8 * 8;
  u16x8 hb, lb;
  #pragma unroll
  for (int j = 0; j < 8; ++j) {
    float v = 0.f;
    if (r < N_NODES && (c + j) < F_IN) v = x[(size_t)r * F_IN + c + j];
    unsigned short h = f2bf(v);
    hb[j] = h; lb[j] = f2bf(v - bf2f(h));
  }
  size_t off = ((size_t)((r >> 7) * KT1 + (c >> 5)) * 4 + ((c >> 3) & 3)) * 1024 + (r & 127) * 8;
  *(u16x8*)&hi[off] = hb;
  *(u16x8*)&lo[off] = lb;
}

// ---------------- W [K][Nsrc] f32 -> hi/lo B-bricks (transposed, k-padded) ----------------
// grid (KT, Ncols/32); rows in brick = rowOffset + n (col index)

__global__ void k_split_w(const float* __restrict__ W,
                          unsigned short* __restrict__ hi, unsigned short* __restrict__ lo,
                          int K, int Nsrc, int c0, int KT, int rowOffset) {
  __shared__ float tile[32][33];
  const int tid = threadIdx.x;
  const int kt = blockIdx.x;
  const int n0 = blockIdx.y * 32;
  #pragma unroll
  for (int i = tid >> 5; i < 32; i += 8) {
    int k = kt * 32 + i;
    tile[i][tid & 31] = (k < K) ? W[(size_t)k * Nsrc + c0 + n0 + (tid & 31)] : 0.f;
  }
  __syncthreads();
  if (tid < 128) {
    const int nn = tid >> 2, kc = (tid & 3) << 3;
    const int n = rowOffset + n0 + nn;
    u16x8 hb, lb;
    #pragma unroll
    for (int j = 0; j < 8; ++j) {
      float v = tile[kc + j][nn];
      unsigned short h = f2bf(v);
      hb[j] = h; lb[j] = f2bf(v - bf2f(h));
    }
    size_t off = ((size_t)((n >> 7) * KT + kt) * 4 + (kc >> 3)) * 1024 + (n & 127) * 8;
    *(u16x8*)&hi[off] = hb;
    *(u16x8*)&lo[off] = lb;
  }
}

// ---------------- split-bf16 GEMM, bricks both sides, 32x32x16 frags ----------------
// 128x128 tile, BK=32, 4 waves 2x2 (wave-tile 64x64 = 2x2 of 32x32).
// Round-4 proven skeleton: single 32KB LDS, 2 barriers/K-step, 3 blocks/CU.

template <int OF16>
__global__ __launch_bounds__(256, 3) void k_gemm_bb(
    const unsigned short* __restrict__ Ahi, const unsigned short* __restrict__ Alo,
    const unsigned short* __restrict__ Bhi, const unsigned short* __restrict__ Blo,
    void* __restrict__ Cp, const float* __restrict__ bias0, const float* __restrict__ bias1,
    int halfN, int M, int ldC, int KT, int gm)
{
  __shared__ __align__(16) unsigned short AhS[4096];
  __shared__ __align__(16) unsigned short AlS[4096];
  __shared__ __align__(16) unsigned short BhS[4096];
  __shared__ __align__(16) unsigned short BlS[4096];

  const int tid = threadIdx.x;
  const int lane = tid & 63;
  const int w = tid >> 6;
  const int wm = w >> 1, wn = w & 1;

  // bijective XCD swizzle; column-major within chunk (blocks share B panel)
  const int chunkg = gridDim.x >> 3;
  const int wg = (blockIdx.x & 7) * chunkg + (blockIdx.x >> 3);
  const int bm = wg % gm, bn = wg / gm;

  f32x16 acc[2][2] = {};

  const unsigned short* AbH = Ahi + (size_t)bm * KT * 4096;
  const unsigned short* AbL = Alo + (size_t)bm * KT * 4096;
  const unsigned short* BbH = Bhi + (size_t)bn * KT * 4096;
  const unsigned short* BbL = Blo + (size_t)bn * KT * 4096;
  const int sOff = w * 1024 + lane * 8;   // per-lane ushort offset within 8KB brick

  const int r5 = lane & 31, h5 = lane >> 5;

  auto stage = [&](int kt) {
    const size_t o = (size_t)kt * 4096 + sOff;
    gload16(AbH + o,       &AhS[w * 1024]);
    gload16(AbH + o + 512, &AhS[w * 1024 + 512]);
    gload16(AbL + o,       &AlS[w * 1024]);
    gload16(AbL + o + 512, &AlS[w * 1024 + 512]);
    gload16(BbH + o,       &BhS[w * 1024]);
    gload16(BbH + o + 512, &BhS[w * 1024 + 512]);
    gload16(BbL + o,       &BlS[w * 1024]);
    gload16(BbL + o + 512, &BlS[w * 1024 + 512]);
  };

  stage(0);
  __syncthreads();

  for (int kt = 0; kt < KT; ++kt) {
    // A frags: row = wm*64 + i*32 + r5, k-chunk plane = kh*2 + h5
    bf16x8 ah[2][2], al[2][2];
    #pragma unroll
    for (int i = 0; i < 2; ++i)
      #pragma unroll
      for (int kh = 0; kh < 2; ++kh) {
        const int ro = (kh * 2 + h5) * 1024 + (wm * 64 + i * 32 + r5) * 8;
        ah[i][kh] = *(const bf16x8*)&AhS[ro];
        al[i][kh] = *(const bf16x8*)&AlS[ro];
      }
    __builtin_amdgcn_s_setprio(1);
    #pragma unroll
    for (int j = 0; j < 2; ++j) {
      #pragma unroll
      for (int kh = 0; kh < 2; ++kh) {
        const int ro = (kh * 2 + h5) * 1024 + (wn * 64 + j * 32 + r5) * 8;
        bf16x8 bh = *(const bf16x8*)&BhS[ro];
        bf16x8 bl = *(const bf16x8*)&BlS[ro];
        #pragma unroll
        for (int i = 0; i < 2; ++i) {
          acc[i][j] = __builtin_amdgcn_mfma_f32_32x32x16_bf16(ah[i][kh], bh, acc[i][j], 0, 0, 0);
          acc[i][j] = __builtin_amdgcn_mfma_f32_32x32x16_bf16(al[i][kh], bh, acc[i][j], 0, 0, 0);
          acc[i][j] = __builtin_amdgcn_mfma_f32_32x32x16_bf16(ah[i][kh], bl, acc[i][j], 0, 0, 0);
        }
      }
    }
    __builtin_amdgcn_s_setprio(0);
    __syncthreads();             // frag reads done
    if (kt + 1 < KT) stage(kt + 1);
    __syncthreads();             // staged tile visible (vmcnt drained here)
  }

  // epilogue: 32x32 C/D layout col=lane&31, row=(reg&3)+8*(reg>>2)+4*(lane>>5)
  #pragma unroll
  for (int i = 0; i < 2; ++i) {
    #pragma unroll
    for (int j = 0; j < 2; ++j) {
      const int gc = bn * 128 + wn * 64 + j * 32 + r5;
      const float bv = (gc < halfN) ? bias0[gc] : bias1[gc - halfN];
      #pragma unroll
      for (int reg = 0; reg < 16; ++reg) {
        const int gr = bm * 128 + wm * 64 + i * 32 + (reg & 3) + 8 * (reg >> 2) + 4 * h5;
        if (gr < M) {
          float v = acc[i][j][reg] + bv;
          if (OF16) ((f16*)Cp)[(size_t)gr * ldC + gc] = (f16)v;
          else      ((float*)Cp)[(size_t)gr * ldC + gc] = v;
        }
      }
    }
  }
}

// ---------------- graph prep ----------------

__global__ void k_deg(const int* __restrict__ dst, const float* __restrict__ ea,
                      float* __restrict__ deg, float* __restrict__ lattr, int E) {
  int e = blockIdx.x * 256 + threadIdx.x;
  if (e >= E) return;
  int d = dst[e];
  atomicAdd(&deg[d], 1.f);
  atomicAdd(&lattr[d * 3 + 0], ea[e * 3 + 0]);
  atomicAdd(&lattr[d * 3 + 1], ea[e * 3 + 1]);
  atomicAdd(&lattr[d * 3 + 2], ea[e * 3 + 2]);
}

__global__ void k_lattr_fin(float* __restrict__ lattr, const float* __restrict__ deg, int n) {
  int i = blockIdx.x * 256 + threadIdx.x;
  if (i >= n) return;
  float dv = fmaxf(deg[i], 1.f);
  lattr[i * 3 + 0] /= dv; lattr[i * 3 + 1] /= dv; lattr[i * 3 + 2] /= dv;
}

__global__ void k_eafull(const float* __restrict__ ea, const float* __restrict__ lattr,
                         float* __restrict__ eaf, int E, int n) {
  int e = blockIdx.x * 256 + threadIdx.x;
  if (e >= E + n) return;
  const float* s = (e < E) ? &ea[(size_t)e * 3] : &lattr[(size_t)(e - E) * 3];
  eaf[e * 3 + 0] = s[0]; eaf[e * 3 + 1] = s[1]; eaf[e * 3 + 2] = s[2];
}

__global__ void k_count(const int* __restrict__ dst, int* __restrict__ cnt, int E, int n) {
  int e = blockIdx.x * 256 + threadIdx.x;
  if (e >= E + n) return;
  int d = (e < E) ? dst[e] : (e - E);
  atomicAdd(&cnt[d], 1);
}

__global__ void k_scan(const int* __restrict__ cnt, int* __restrict__ rowptr, int n) {
  int lane = threadIdx.x;   // 64 threads, 1 block
  int run = 0;
  for (int base = 0; base < n; base += 64) {
    int i = base + lane;
    int v = (i < n) ? cnt[i] : 0;
    #pragma unroll
    for (int off = 1; off < 64; off <<= 1) {
      int t = __shfl_up(v, off, 64);
      if (lane >= off) v += t;
    }
    if (i < n) rowptr[i + 1] = run + v;
    run += __shfl(v, 63, 64);
  }
  if (lane == 0) rowptr[0] = 0;
}

__global__ void k_fill(const int* __restrict__ dst, const int* __restrict__ rowptr,
                       int* __restrict__ fillc, int* __restrict__ elist, int E, int n) {
  int e = blockIdx.x * 256 + threadIdx.x;
  if (e >= E + n) return;
  int d = (e < E) ? dst[e] : (e - E);
  int pos = rowptr[d] + atomicAdd(&fillc[d], 1);
  elist[pos] = e;
}

// ---------------- GATv2 edge phase (xl/xr in f16, math f32) ----------------

template <int H, int ITERS>
__global__ __launch_bounds__(256) void k_logit(
    const f16* __restrict__ xl, const f16* __restrict__ xr, int strideX,
    const float* __restrict__ eaf, const float* __restrict__ We, const float* __restrict__ att,
    const int* __restrict__ src, const int* __restrict__ dst, int E,
    float* __restrict__ logit)
{
  const int e = blockIdx.x;
  const int tid = threadIdx.x;
  int s, d;
  if (e < E) { s = src[e]; d = dst[e]; } else { s = e - E; d = s; }
  const float ea0 = eaf[e * 3 + 0], ea1 = eaf[e * 3 + 1], ea2 = eaf[e * 3 + 2];
  constexpr int HC = ITERS * 256;
  const f16* rl = xl + (size_t)s * strideX;
  const f16* rr = xr + (size_t)d * strideX;
  float acc[H];
  #pragma unroll
  for (int h = 0; h < H; ++h) acc[h] = 0.f;
  #pragma unroll
  for (int i = 0; i < ITERS; ++i) {
    int hc = tid + (i << 8);
    float v = (float)rl[hc] + (float)rr[hc]
            + ea0 * We[hc] + ea1 * We[HC + hc] + ea2 * We[2 * HC + hc];
    v = (v > 0.f) ? v : 0.2f * v;
    acc[i >> 2] += v * att[hc];
  }
  __shared__ float red[H][4];
  const int lane = tid & 63, wv = tid >> 6;
  #pragma unroll
  for (int h = 0; h < H; ++h) {
    float v = acc[h];
    #pragma unroll
    for (int off = 32; off > 0; off >>= 1) v += __shfl_down(v, off, 64);
    if (lane == 0) red[h][wv] = v;
  }
  __syncthreads();
  if (tid < H)
    logit[(size_t)e * H + tid] = red[tid][0] + red[tid][1] + red[tid][2] + red[tid][3];
}

template <int H>
__global__ void k_stats(const float* __restrict__ logit, const int* __restrict__ rowptr,
                        const int* __restrict__ elist, float* __restrict__ mb, float* __restrict__ db)
{
  const int n = blockIdx.x;
  const int lane = threadIdx.x;   // 64
  const int start = rowptr[n], end = rowptr[n + 1];
  #pragma unroll
  for (int h = 0; h < H; ++h) {
    float m = -1e30f;
    for (int p = start + lane; p < end; p += 64)
      m = fmaxf(m, logit[(size_t)elist[p] * H + h]);
    #pragma unroll
    for (int off = 32; off > 0; off >>= 1) m = fmaxf(m, __shfl_down(m, off, 64));
    m = __shfl(m, 0, 64);
    float sum = 0.f;
    for (int p = start + lane; p < end; p += 64)
      sum += __expf(logit[(size_t)elist[p] * H + h] - m);
    #pragma unroll
    for (int off = 32; off > 0; off >>= 1) sum += __shfl_down(sum, off, 64);
    if (lane == 0) { mb[n * H + h] = m; db[n * H + h] = sum; }
  }
}

// out[n][hc] = sum_e alpha*xl[src][hc] + bias, stored as hi/lo A-bricks for next GEMM
template <int H, int NC8, int KTo>
__global__ __launch_bounds__(256) void k_agg(
    const f16* __restrict__ xl, int strideX,
    const int* __restrict__ rowptr, const int* __restrict__ elist, const int* __restrict__ src,
    const float* __restrict__ logit, const float* __restrict__ mb, const float* __restrict__ db,
    const float* __restrict__ bias,
    unsigned short* __restrict__ ohi, unsigned short* __restrict__ olo, int E)
{
  const int n = blockIdx.x;
  const int tid = threadIdx.x;
  constexpr int HC = H * 1024;
  float acc[NC8][8];
  #pragma unroll
  for (int q = 0; q < NC8; ++q)
    #pragma unroll
    for (int j = 0; j < 8; ++j) acc[q][j] = 0.f;
  const int start = rowptr[n], end = rowptr[n + 1];
  float mloc[H], dloc[H];
  #pragma unroll
  for (int h = 0; h < H; ++h) { mloc[h] = mb[n * H + h]; dloc[h] = db[n * H + h] + 1e-16f; }
  for (int p = start; p < end; ++p) {
    const int e = elist[p];
    const int s = (e < E) ? src[e] : (e - E);
    float al[H];
    #pragma unroll
    for (int h = 0; h < H; ++h)
      al[h] = __expf(logit[(size_t)e * H + h] - mloc[h]) / dloc[h];
    const f16* row = xl + (size_t)s * strideX;
    #pragma unroll
    for (int q = 0; q < NC8; ++q) {
      const int c8 = tid + q * 256;
      if (c8 * 8 < HC) {
        float a = (H == 4) ? ((tid & 128) ? al[2 * q + 1] : al[2 * q]) : al[0];
        f16x8 v = *(const f16x8*)(row + c8 * 8);
        #pragma unroll
        for (int j = 0; j < 8; ++j) acc[q][j] += a * (float)v[j];
      }
    }
  }
  #pragma unroll
  for (int q = 0; q < NC8; ++q) {
    const int c8 = tid + q * 256;
    if (c8 * 8 < HC) {
      u16x8 hb, lb;
      #pragma unroll
      for (int j = 0; j < 8; ++j) {
        float v = acc[q][j] + bias[c8 * 8 + j];
        unsigned short h = f2bf(v);
        hb[j] = h; lb[j] = f2bf(v - bf2f(h));
      }
      size_t off = ((size_t)((n >> 7) * KTo + (c8 >> 2)) * 4 + (c8 & 3)) * 1024 + (n & 127) * 8;
      *(u16x8*)&ohi[off] = hb;
      *(u16x8*)&olo[off] = lb;
    }
  }
}

// ---------------- launch ----------------

extern "C" void kernel_launch(void* const* d_in, const int* in_sizes, int n_in,
                              void* d_out, int out_size, void* d_ws, size_t ws_size,
                              hipStream_t stream) {
  const float* x    = (const float*)d_in[0];
  const int*   eidx = (const int*)d_in[1];
  const float* eattr= (const float*)d_in[2];
  const float* W1l  = (const float*)d_in[3];
  const float* b1l  = (const float*)d_in[4];
  const float* W1r  = (const float*)d_in[5];
  const float* b1r  = (const float*)d_in[6];
  const float* W1e  = (const float*)d_in[7];
  const float* att1 = (const float*)d_in[8];
  const float* bias1= (const float*)d_in[9];
  const float* W2l  = (const float*)d_in[10];
  const float* b2l  = (const float*)d_in[11];
  const float* W2r  = (const float*)d_in[12];
  const float* b2r  = (const float*)d_in[13];
  const float* W2e  = (const float*)d_in[14];
  const float* att2 = (const float*)d_in[15];
  const float* bias2= (const float*)d_in[16];
  const float* Wlin = (const float*)d_in[17];
  const float* blin = (const float*)d_in[18];
  float* out = (float*)d_out;

  char* ws = (char*)d_ws;
  const int* srcp = eidx;
  const int* dstp = eidx + E_EDGES;

  auto alignup = [](size_t v) { return (v + 255) & ~(size_t)255; };

  // ---- layout (~368 MB, fits proven >=370.9 MB budget) ----
  const size_t oXHI = 0;                                    // A bricks hi: 79.0 MB
  const size_t oXLO = oXHI + (size_t)MP * KP1 * 2;          // A bricks lo: 79.0 MB
  const size_t oXLR = oXLO + (size_t)MP * KP1 * 2;          // xl|xr f16 [5000][8192]: 82 MB
  const size_t oBH  = oXLR + (size_t)N_NODES * N1 * 2;      // B bricks hi (4096 cols): 63.2 MB
  const size_t oBL  = oBH + (size_t)4096 * KP1 * 2;         // B bricks lo: 63.2 MB
  const size_t oS   = oBL + (size_t)4096 * KP1 * 2;
  const size_t oLATTR = alignup(oS);
  const size_t oDEG   = alignup(oLATTR + (size_t)N_NODES * 3 * 4);
  const size_t oEAF   = alignup(oDEG + (size_t)N_NODES * 4);
  const size_t oCNT   = alignup(oEAF + (size_t)EFULL * 3 * 4);
  const size_t oROW   = alignup(oCNT + (size_t)N_NODES * 4);
  const size_t oFILL  = alignup(oROW + (size_t)(N_NODES + 1) * 4);
  const size_t oELIST = alignup(oFILL + (size_t)N_NODES * 4);
  const size_t oLOGIT = alignup(oELIST + (size_t)EFULL * 4);
  const size_t oMB    = alignup(oLOGIT + (size_t)EFULL * 4 * 4);
  const size_t oDB    = alignup(oMB + (size_t)N_NODES * 4 * 4);
  const size_t oEND   = alignup(oDB + (size_t)N_NODES * 4 * 4);
  if (ws_size < oEND) return;

  // overlays (free by write time)
  const size_t oH1HI = oXHI;                            // H1 bricks: 41.9 MB (in 79)
  const size_t oH1LO = oXLO;
  const size_t oXLR2 = oXLR;                            // xl2|xr2 f16 [5000][2048]: 20.5 MB
  const size_t oH2HI = oXLR + 32ull * 1024 * 1024;      // H2 bricks: 10.5 MB
  const size_t oH2LO = oXLR + 48ull * 1024 * 1024;      // 10.5 MB
  const size_t oB2H  = oBH;                             // W2 bricks: 16.8 MB (in 63)
  const size_t oB2L  = oBL;
  const size_t oB3H  = oBH;                             // Wlin bricks: 0.26 MB
  const size_t oB3L  = oBH + 1ull * 1024 * 1024;

  unsigned short* XHI  = (unsigned short*)(ws + oXHI);
  unsigned short* XLO  = (unsigned short*)(ws + oXLO);
  f16*            XLR  = (f16*)(ws + oXLR);
  unsigned short* BH   = (unsigned short*)(ws + oBH);
  unsigned short* BL   = (unsigned short*)(ws + oBL);
  float*          LATTR= (float*)(ws + oLATTR);
  float*          DEG  = (float*)(ws + oDEG);
  float*          EAF  = (float*)(ws + oEAF);
  int*            CNT  = (int*)(ws + oCNT);
  int*            ROWP = (int*)(ws + oROW);
  int*            FILLC= (int*)(ws + oFILL);
  int*            ELIST= (int*)(ws + oELIST);
  float*          LOGIT= (float*)(ws + oLOGIT);
  float*          MB   = (float*)(ws + oMB);
  float*          DB   = (float*)(ws + oDB);
  unsigned short* H1HI = (unsigned short*)(ws + oH1HI);
  unsigned short* H1LO = (unsigned short*)(ws + oH1LO);
  f16*            XLR2 = (f16*)(ws + oXLR2);
  unsigned short* H2HI = (unsigned short*)(ws + oH2HI);
  unsigned short* H2LO = (unsigned short*)(ws + oH2LO);
  unsigned short* B2H  = (unsigned short*)(ws + oB2H);
  unsigned short* B2L  = (unsigned short*)(ws + oB2L);
  unsigned short* B3H  = (unsigned short*)(ws + oB3H);
  unsigned short* B3L  = (unsigned short*)(ws + oB3L);

  hipMemsetAsync(ws + oDEG,   0, (size_t)N_NODES * 4, stream);
  hipMemsetAsync(ws + oLATTR, 0, (size_t)N_NODES * 3 * 4, stream);
  hipMemsetAsync(ws + oCNT,   0, (size_t)N_NODES * 4, stream);
  hipMemsetAsync(ws + oFILL,  0, (size_t)N_NODES * 4, stream);

  const int gE  = (E_EDGES + 255) / 256;
  const int gEF = (EFULL + 255) / 256;
  const int gN  = (N_NODES + 255) / 256;

  // ---- graph structure ----
  k_deg<<<gE, 256, 0, stream>>>(dstp, eattr, DEG, LATTR, E_EDGES);
  k_lattr_fin<<<gN, 256, 0, stream>>>(LATTR, DEG, N_NODES);
  k_eafull<<<gEF, 256, 0, stream>>>(eattr, LATTR, EAF, E_EDGES, N_NODES);
  k_count<<<gEF, 256, 0, stream>>>(dstp, CNT, E_EDGES, N_NODES);
  k_scan<<<1, 64, 0, stream>>>(CNT, ROWP, N_NODES);
  k_fill<<<gEF, 256, 0, stream>>>(dstp, ROWP, FILLC, ELIST, E_EDGES, N_NODES);

  // ---- layer 1: A bricks, then W1l half / W1r half ----
  k_split_x<<<MP * (KP1 / 8) / 256, 256, 0, stream>>>(x, XHI, XLO);

  k_split_w<<<dim3(KT1, HC1 / 32), 256, 0, stream>>>(W1l, BH, BL, F_IN, HC1, 0, KT1, 0);
  k_gemm_bb<1><<<(HC1 / 128) * (MP / 128), 256, 0, stream>>>(
      XHI, XLO, BH, BL, XLR, b1l, b1l, HC1, N_NODES, N1, KT1, MP / 128);

  k_split_w<<<dim3(KT1, HC1 / 32), 256, 0, stream>>>(W1r, BH, BL, F_IN, HC1, 0, KT1, 0);
  k_gemm_bb<1><<<(HC1 / 128) * (MP / 128), 256, 0, stream>>>(
      XHI, XLO, BH, BL, XLR + HC1, b1r, b1r, HC1, N_NODES, N1, KT1, MP / 128);

  // ---- layer 1 attention + aggregation ----
  k_logit<4, 16><<<EFULL, 256, 0, stream>>>(XLR, XLR + HC1, N1, EAF, W1e, att1, srcp, dstp, E_EDGES, LOGIT);
  k_stats<4><<<N_NODES, 64, 0, stream>>>(LOGIT, ROWP, ELIST, MB, DB);
  hipMemsetAsync(ws + oH1HI, 0, (size_t)MP * HC1 * 2, stream);
  hipMemsetAsync(ws + oH1LO, 0, (size_t)MP * HC1 * 2, stream);
  k_agg<4, 2, HC1 / 32><<<N_NODES, 256, 0, stream>>>(
      XLR, N1, ROWP, ELIST, srcp, LOGIT, MB, DB, bias1, H1HI, H1LO, E_EDGES);

  // ---- layer 2 ----
  k_split_w<<<dim3(HC1 / 32, HC2 / 32), 256, 0, stream>>>(W2l, B2H, B2L, HC1, HC2, 0, HC1 / 32, 0);
  k_split_w<<<dim3(HC1 / 32, HC2 / 32), 256, 0, stream>>>(W2r, B2H, B2L, HC1, HC2, 0, HC1 / 32, HC2);
  k_gemm_bb<1><<<(N2 / 128) * (MP / 128), 256, 0, stream>>>(
      H1HI, H1LO, B2H, B2L, XLR2, b2l, b2r, HC2, N_NODES, N2, HC1 / 32, MP / 128);

  k_logit<1, 4><<<EFULL, 256, 0, stream>>>(XLR2, XLR2 + HC2, N2, EAF, W2e, att2, srcp, dstp, E_EDGES, LOGIT);
  k_stats<1><<<N_NODES, 64, 0, stream>>>(LOGIT, ROWP, ELIST, MB, DB);
  hipMemsetAsync(ws + oH2HI, 0, (size_t)MP * HC2 * 2, stream);
  hipMemsetAsync(ws + oH2LO, 0, (size_t)MP * HC2 * 2, stream);
  k_agg<1, 1, HC2 / 32><<<N_NODES, 256, 0, stream>>>(
      XLR2, N2, ROWP, ELIST, srcp, LOGIT, MB, DB, bias2, H2HI, H2LO, E_EDGES);

  // ---- final linear ----
  k_split_w<<<dim3(HC2 / 32, NOUT / 32), 256, 0, stream>>>(Wlin, B3H, B3L, HC2, NOUT, 0, HC2 / 32, 0);
  k_gemm_bb<0><<<(NOUT / 128) * (MP / 128), 256, 0, stream>>>(
      H2HI, H2LO, B3H, B3L, out, blin, blin, NOUT, N_NODES, NOUT, HC2 / 32, MP / 128);
}

// Round 7
// 2867.677 us; speedup vs baseline: 1.1871x; 1.0451x over previous
//
#include <hip/hip_runtime.h>
#include <cstdint>
#include <cstddef>

#define N_NODES 5000
#define F_IN    7699
#define KP1     7712   // F_IN padded to mult of 32
#define KT1     241    // KP1/32
#define MP      5120   // rows padded to mult of 128
#define E_EDGES 40000
#define EFULL   45000  // E + N self loops
#define HC1     4096   // heads1*ch1
#define N1      8192   // xl|xr concat
#define HC2     1024
#define N2      2048
#define NOUT    128

typedef __bf16 bf16x8 __attribute__((ext_vector_type(8)));
typedef float  f32x4  __attribute__((ext_vector_type(4)));
typedef float  f32x16 __attribute__((ext_vector_type(16)));
typedef unsigned short u16x8 __attribute__((ext_vector_type(8)));
typedef _Float16 f16;
typedef _Float16 f16x8 __attribute__((ext_vector_type(8)));

using as1_uchar = unsigned char __attribute__((address_space(1)));
using as3_uchar = unsigned char __attribute__((address_space(3)));

__device__ __forceinline__ unsigned short f2bf(float f) {
  union { float f; unsigned int u; } v; v.f = f;
  return (unsigned short)((v.u + 0x7fffu + ((v.u >> 16) & 1u)) >> 16);
}
__device__ __forceinline__ float bf2f(unsigned short h) {
  union { unsigned int u; float f; } v; v.u = ((unsigned int)h) << 16;
  return v.f;
}

__device__ __forceinline__ void gload16(const void* g, void* l) {
  __builtin_amdgcn_global_load_lds(
      reinterpret_cast<const as1_uchar*>(reinterpret_cast<uintptr_t>(g)),
      reinterpret_cast<as3_uchar*>(reinterpret_cast<uintptr_t>(l)),
      16, 0, 0);
}

// Brick layout (global == LDS chunk-plane, zero conflicts):
// element (row r, k c) -> ((r>>7)*KT + (c>>5))*4096 + (((c>>3)&3))*1024 + (r&127)*8 + (c&7)

// ---------------- x -> hi/lo A-bricks ----------------

__global__ void k_split_x(const float* __restrict__ x, unsigned short* __restrict__ hi,
                          unsigned short* __restrict__ lo) {
  const int C8 = KP1 / 8;                       // 964
  int ci = blockIdx.x * 256 + threadIdx.x;
  if (ci >= MP * C8) return;
  int r = ci / C8, c8 = ci % C8;
  int c = c8 * 8;
  u16x8 hb, lb;
  #pragma unroll
  for (int j = 0; j < 8; ++j) {
    float v = 0.f;
    if (r < N_NODES && (c + j) < F_IN) v = x[(size_t)r * F_IN + c + j];
    unsigned short h = f2bf(v);
    hb[j] = h; lb[j] = f2bf(v - bf2f(h));
  }
  size_t off = ((size_t)((r >> 7) * KT1 + (c >> 5)) * 4 + ((c >> 3) & 3)) * 1024 + (r & 127) * 8;
  *(u16x8*)&hi[off] = hb;
  *(u16x8*)&lo[off] = lb;
}

// ---------------- W [K][Nsrc] f32 -> hi/lo B-bricks (transposed, k-padded) ----------------

__global__ void k_split_w(const float* __restrict__ W,
                          unsigned short* __restrict__ hi, unsigned short* __restrict__ lo,
                          int K, int Nsrc, int c0, int KT, int rowOffset) {
  __shared__ float tile[32][33];
  const int tid = threadIdx.x;
  const int kt = blockIdx.x;
  const int n0 = blockIdx.y * 32;
  #pragma unroll
  for (int i = tid >> 5; i < 32; i += 8) {
    int k = kt * 32 + i;
    tile[i][tid & 31] = (k < K) ? W[(size_t)k * Nsrc + c0 + n0 + (tid & 31)] : 0.f;
  }
  __syncthreads();
  if (tid < 128) {
    const int nn = tid >> 2, kc = (tid & 3) << 3;
    const int n = rowOffset + n0 + nn;
    u16x8 hb, lb;
    #pragma unroll
    for (int j = 0; j < 8; ++j) {
      float v = tile[kc + j][nn];
      unsigned short h = f2bf(v);
      hb[j] = h; lb[j] = f2bf(v - bf2f(h));
    }
    size_t off = ((size_t)((n >> 7) * KT + kt) * 4 + (kc >> 3)) * 1024 + (n & 127) * 8;
    *(u16x8*)&hi[off] = hb;
    *(u16x8*)&lo[off] = lb;
  }
}

// ---------------- split-bf16 GEMM, bricks both sides, 32x32x16, dbuf+counted-vmcnt ----------------
// 128x128 tile, BK=32, 4 waves 2x2 (wave-tile 64x64). LDS 64KB dbuf, 2 blocks/CU.
// Pipeline: stage(kt+2) issued before MFMA(kt); end-of-iter waits vmcnt(8) -> drains
// only stage(kt+1) (issued a full iteration earlier); stage(kt+2) stays in flight.

template <int OF16>
__global__ __launch_bounds__(256, 2) void k_gemm_bb(
    const unsigned short* __restrict__ Ahi, const unsigned short* __restrict__ Alo,
    const unsigned short* __restrict__ Bhi, const unsigned short* __restrict__ Blo,
    void* __restrict__ Cp, const float* __restrict__ bias0, const float* __restrict__ bias1,
    int halfN, int M, int ldC, int KT, int gn)
{
  __shared__ __align__(16) unsigned short AhS[2 * 4096];
  __shared__ __align__(16) unsigned short AlS[2 * 4096];
  __shared__ __align__(16) unsigned short BhS[2 * 4096];
  __shared__ __align__(16) unsigned short BlS[2 * 4096];

  const int tid = threadIdx.x;
  const int lane = tid & 63;
  const int w = tid >> 6;
  const int wm = w >> 1, wn = w & 1;

  // band-major order: 8 bm-rows x all bn per band (A-band + B fit in L3)
  const int s = blockIdx.x;
  const int band = s / (8 * gn);
  const int r = s % (8 * gn);
  const int bn = r >> 3;
  const int bm = band * 8 + (r & 7);

  f32x16 acc[2][2] = {};

  const unsigned short* AbH = Ahi + (size_t)bm * KT * 4096;
  const unsigned short* AbL = Alo + (size_t)bm * KT * 4096;
  const unsigned short* BbH = Bhi + (size_t)bn * KT * 4096;
  const unsigned short* BbL = Blo + (size_t)bn * KT * 4096;
  const int sOff = w * 1024 + lane * 8;   // per-lane ushort offset within 8KB brick

  const int r5 = lane & 31, h5 = lane >> 5;

  auto stage = [&](int kt, int p) {
    const size_t o = (size_t)kt * 4096 + sOff;
    const int lp = p * 4096 + w * 1024;
    gload16(AbH + o,       &AhS[lp]);
    gload16(AbH + o + 512, &AhS[lp + 512]);
    gload16(AbL + o,       &AlS[lp]);
    gload16(AbL + o + 512, &AlS[lp + 512]);
    gload16(BbH + o,       &BhS[lp]);
    gload16(BbH + o + 512, &BhS[lp + 512]);
    gload16(BbL + o,       &BlS[lp]);
    gload16(BbL + o + 512, &BlS[lp + 512]);
  };

  // prologue: two tiles in flight; wait only the first (8 newest remain outstanding)
  stage(0, 0);
  stage(1, 1);
  asm volatile("s_waitcnt vmcnt(8)" ::: "memory");
  __builtin_amdgcn_s_barrier();

  for (int kt = 0; kt < KT; ++kt) {
    const int p = kt & 1;
    // read all 16 frags of tile kt from buf p
    bf16x8 ah[2][2], al[2][2], bh[2][2], bl[2][2];
    #pragma unroll
    for (int i = 0; i < 2; ++i)
      #pragma unroll
      for (int kh = 0; kh < 2; ++kh) {
        const int ro = p * 4096 + (kh * 2 + h5) * 1024 + (wm * 64 + i * 32 + r5) * 8;
        ah[i][kh] = *(const bf16x8*)&AhS[ro];
        al[i][kh] = *(const bf16x8*)&AlS[ro];
      }
    #pragma unroll
    for (int j = 0; j < 2; ++j)
      #pragma unroll
      for (int kh = 0; kh < 2; ++kh) {
        const int ro = p * 4096 + (kh * 2 + h5) * 1024 + (wn * 64 + j * 32 + r5) * 8;
        bh[j][kh] = *(const bf16x8*)&BhS[ro];
        bl[j][kh] = *(const bf16x8*)&BlS[ro];
      }
    // all waves done reading buf p -> safe to overwrite with tile kt+2
    asm volatile("s_waitcnt lgkmcnt(0)" ::: "memory");
    __builtin_amdgcn_s_barrier();
    const int ks = (kt + 2 < KT) ? kt + 2 : KT - 1;   // tail: harmless re-stage, keeps vmcnt uniform
    stage(ks, p);

    __builtin_amdgcn_s_setprio(1);
    #pragma unroll
    for (int j = 0; j < 2; ++j)
      #pragma unroll
      for (int kh = 0; kh < 2; ++kh)
        #pragma unroll
        for (int i = 0; i < 2; ++i) {
          acc[i][j] = __builtin_amdgcn_mfma_f32_32x32x16_bf16(ah[i][kh], bh[j][kh], acc[i][j], 0, 0, 0);
          acc[i][j] = __builtin_amdgcn_mfma_f32_32x32x16_bf16(al[i][kh], bh[j][kh], acc[i][j], 0, 0, 0);
          acc[i][j] = __builtin_amdgcn_mfma_f32_32x32x16_bf16(ah[i][kh], bl[j][kh], acc[i][j], 0, 0, 0);
        }
    __builtin_amdgcn_s_setprio(0);

    // drain only stage(kt+1) (issued last iteration); stage(kt+2) stays in flight
    asm volatile("s_waitcnt vmcnt(8)" ::: "memory");
    __builtin_amdgcn_s_barrier();
  }

  // epilogue: 32x32 C/D layout col=lane&31, row=(reg&3)+8*(reg>>2)+4*(lane>>5)
  #pragma unroll
  for (int i = 0; i < 2; ++i) {
    #pragma unroll
    for (int j = 0; j < 2; ++j) {
      const int gc = bn * 128 + wn * 64 + j * 32 + r5;
      const float bv = (gc < halfN) ? bias0[gc] : bias1[gc - halfN];
      #pragma unroll
      for (int reg = 0; reg < 16; ++reg) {
        const int gr = bm * 128 + wm * 64 + i * 32 + (reg & 3) + 8 * (reg >> 2) + 4 * h5;
        if (gr < M) {
          float v = acc[i][j][reg] + bv;
          if (OF16) ((f16*)Cp)[(size_t)gr * ldC + gc] = (f16)v;
          else      ((float*)Cp)[(size_t)gr * ldC + gc] = v;
        }
      }
    }
  }
}

// ---------------- graph prep ----------------

__global__ void k_deg(const int* __restrict__ dst, const float* __restrict__ ea,
                      float* __restrict__ deg, float* __restrict__ lattr, int E) {
  int e = blockIdx.x * 256 + threadIdx.x;
  if (e >= E) return;
  int d = dst[e];
  atomicAdd(&deg[d], 1.f);
  atomicAdd(&lattr[d * 3 + 0], ea[e * 3 + 0]);
  atomicAdd(&lattr[d * 3 + 1], ea[e * 3 + 1]);
  atomicAdd(&lattr[d * 3 + 2], ea[e * 3 + 2]);
}

__global__ void k_lattr_fin(float* __restrict__ lattr, const float* __restrict__ deg, int n) {
  int i = blockIdx.x * 256 + threadIdx.x;
  if (i >= n) return;
  float dv = fmaxf(deg[i], 1.f);
  lattr[i * 3 + 0] /= dv; lattr[i * 3 + 1] /= dv; lattr[i * 3 + 2] /= dv;
}

__global__ void k_eafull(const float* __restrict__ ea, const float* __restrict__ lattr,
                         float* __restrict__ eaf, int E, int n) {
  int e = blockIdx.x * 256 + threadIdx.x;
  if (e >= E + n) return;
  const float* s = (e < E) ? &ea[(size_t)e * 3] : &lattr[(size_t)(e - E) * 3];
  eaf[e * 3 + 0] = s[0]; eaf[e * 3 + 1] = s[1]; eaf[e * 3 + 2] = s[2];
}

__global__ void k_count(const int* __restrict__ dst, int* __restrict__ cnt, int E, int n) {
  int e = blockIdx.x * 256 + threadIdx.x;
  if (e >= E + n) return;
  int d = (e < E) ? dst[e] : (e - E);
  atomicAdd(&cnt[d], 1);
}

__global__ void k_scan(const int* __restrict__ cnt, int* __restrict__ rowptr, int n) {
  int lane = threadIdx.x;   // 64 threads, 1 block
  int run = 0;
  for (int base = 0; base < n; base += 64) {
    int i = base + lane;
    int v = (i < n) ? cnt[i] : 0;
    #pragma unroll
    for (int off = 1; off < 64; off <<= 1) {
      int t = __shfl_up(v, off, 64);
      if (lane >= off) v += t;
    }
    if (i < n) rowptr[i + 1] = run + v;
    run += __shfl(v, 63, 64);
  }
  if (lane == 0) rowptr[0] = 0;
}

__global__ void k_fill(const int* __restrict__ dst, const int* __restrict__ rowptr,
                       int* __restrict__ fillc, int* __restrict__ elist, int E, int n) {
  int e = blockIdx.x * 256 + threadIdx.x;
  if (e >= E + n) return;
  int d = (e < E) ? dst[e] : (e - E);
  int pos = rowptr[d] + atomicAdd(&fillc[d], 1);
  elist[pos] = e;
}

// ---------------- GATv2 edge phase (xl/xr in f16, math f32) ----------------

template <int H, int ITERS>
__global__ __launch_bounds__(256) void k_logit(
    const f16* __restrict__ xl, const f16* __restrict__ xr, int strideX,
    const float* __restrict__ eaf, const float* __restrict__ We, const float* __restrict__ att,
    const int* __restrict__ src, const int* __restrict__ dst, int E,
    float* __restrict__ logit)
{
  const int e = blockIdx.x;
  const int tid = threadIdx.x;
  int s, d;
  if (e < E) { s = src[e]; d = dst[e]; } else { s = e - E; d = s; }
  const float ea0 = eaf[e * 3 + 0], ea1 = eaf[e * 3 + 1], ea2 = eaf[e * 3 + 2];
  constexpr int HC = ITERS * 256;
  const f16* rl = xl + (size_t)s * strideX;
  const f16* rr = xr + (size_t)d * strideX;
  float acc[H];
  #pragma unroll
  for (int h = 0; h < H; ++h) acc[h] = 0.f;
  #pragma unroll
  for (int i = 0; i < ITERS; ++i) {
    int hc = tid + (i << 8);
    float v = (float)rl[hc] + (float)rr[hc]
            + ea0 * We[hc] + ea1 * We[HC + hc] + ea2 * We[2 * HC + hc];
    v = (v > 0.f) ? v : 0.2f * v;
    acc[i >> 2] += v * att[hc];
  }
  __shared__ float red[H][4];
  const int lane = tid & 63, wv = tid >> 6;
  #pragma unroll
  for (int h = 0; h < H; ++h) {
    float v = acc[h];
    #pragma unroll
    for (int off = 32; off > 0; off >>= 1) v += __shfl_down(v, off, 64);
    if (lane == 0) red[h][wv] = v;
  }
  __syncthreads();
  if (tid < H)
    logit[(size_t)e * H + tid] = red[tid][0] + red[tid][1] + red[tid][2] + red[tid][3];
}

template <int H>
__global__ void k_stats(const float* __restrict__ logit, const int* __restrict__ rowptr,
                        const int* __restrict__ elist, float* __restrict__ mb, float* __restrict__ db)
{
  const int n = blockIdx.x;
  const int lane = threadIdx.x;   // 64
  const int start = rowptr[n], end = rowptr[n + 1];
  #pragma unroll
  for (int h = 0; h < H; ++h) {
    float m = -1e30f;
    for (int p = start + lane; p < end; p += 64)
      m = fmaxf(m, logit[(size_t)elist[p] * H + h]);
    #pragma unroll
    for (int off = 32; off > 0; off >>= 1) m = fmaxf(m, __shfl_down(m, off, 64));
    m = __shfl(m, 0, 64);
    float sum = 0.f;
    for (int p = start + lane; p < end; p += 64)
      sum += __expf(logit[(size_t)elist[p] * H + h] - m);
    #pragma unroll
    for (int off = 32; off > 0; off >>= 1) sum += __shfl_down(sum, off, 64);
    if (lane == 0) { mb[n * H + h] = m; db[n * H + h] = sum; }
  }
}

// out[n][hc] = sum_e alpha*xl[src][hc] + bias, stored as hi/lo A-bricks for next GEMM
template <int H, int NC8, int KTo>
__global__ __launch_bounds__(256) void k_agg(
    const f16* __restrict__ xl, int strideX,
    const int* __restrict__ rowptr, const int* __restrict__ elist, const int* __restrict__ src,
    const float* __restrict__ logit, const float* __restrict__ mb, const float* __restrict__ db,
    const float* __restrict__ bias,
    unsigned short* __restrict__ ohi, unsigned short* __restrict__ olo, int E)
{
  const int n = blockIdx.x;
  const int tid = threadIdx.x;
  constexpr int HC = H * 1024;
  float acc[NC8][8];
  #pragma unroll
  for (int q = 0; q < NC8; ++q)
    #pragma unroll
    for (int j = 0; j < 8; ++j) acc[q][j] = 0.f;
  const int start = rowptr[n], end = rowptr[n + 1];
  float mloc[H], dloc[H];
  #pragma unroll
  for (int h = 0; h < H; ++h) { mloc[h] = mb[n * H + h]; dloc[h] = db[n * H + h] + 1e-16f; }
  for (int p = start; p < end; ++p) {
    const int e = elist[p];
    const int s = (e < E) ? src[e] : (e - E);
    float al[H];
    #pragma unroll
    for (int h = 0; h < H; ++h)
      al[h] = __expf(logit[(size_t)e * H + h] - mloc[h]) / dloc[h];
    const f16* row = xl + (size_t)s * strideX;
    #pragma unroll
    for (int q = 0; q < NC8; ++q) {
      const int c8 = tid + q * 256;
      if (c8 * 8 < HC) {
        float a = (H == 4) ? ((tid & 128) ? al[2 * q + 1] : al[2 * q]) : al[0];
        f16x8 v = *(const f16x8*)(row + c8 * 8);
        #pragma unroll
        for (int j = 0; j < 8; ++j) acc[q][j] += a * (float)v[j];
      }
    }
  }
  #pragma unroll
  for (int q = 0; q < NC8; ++q) {
    const int c8 = tid + q * 256;
    if (c8 * 8 < HC) {
      u16x8 hb, lb;
      #pragma unroll
      for (int j = 0; j < 8; ++j) {
        float v = acc[q][j] + bias[c8 * 8 + j];
        unsigned short h = f2bf(v);
        hb[j] = h; lb[j] = f2bf(v - bf2f(h));
      }
      size_t off = ((size_t)((n >> 7) * KTo + (c8 >> 2)) * 4 + (c8 & 3)) * 1024 + (n & 127) * 8;
      *(u16x8*)&ohi[off] = hb;
      *(u16x8*)&olo[off] = lb;
    }
  }
}

// ---------------- launch ----------------

extern "C" void kernel_launch(void* const* d_in, const int* in_sizes, int n_in,
                              void* d_out, int out_size, void* d_ws, size_t ws_size,
                              hipStream_t stream) {
  const float* x    = (const float*)d_in[0];
  const int*   eidx = (const int*)d_in[1];
  const float* eattr= (const float*)d_in[2];
  const float* W1l  = (const float*)d_in[3];
  const float* b1l  = (const float*)d_in[4];
  const float* W1r  = (const float*)d_in[5];
  const float* b1r  = (const float*)d_in[6];
  const float* W1e  = (const float*)d_in[7];
  const float* att1 = (const float*)d_in[8];
  const float* bias1= (const float*)d_in[9];
  const float* W2l  = (const float*)d_in[10];
  const float* b2l  = (const float*)d_in[11];
  const float* W2r  = (const float*)d_in[12];
  const float* b2r  = (const float*)d_in[13];
  const float* W2e  = (const float*)d_in[14];
  const float* att2 = (const float*)d_in[15];
  const float* bias2= (const float*)d_in[16];
  const float* Wlin = (const float*)d_in[17];
  const float* blin = (const float*)d_in[18];
  float* out = (float*)d_out;

  char* ws = (char*)d_ws;
  const int* srcp = eidx;
  const int* dstp = eidx + E_EDGES;

  auto alignup = [](size_t v) { return (v + 255) & ~(size_t)255; };

  // ---- layout (~368 MB) ----
  const size_t oXHI = 0;                                    // A bricks hi: 79.0 MB
  const size_t oXLO = oXHI + (size_t)MP * KP1 * 2;          // A bricks lo: 79.0 MB
  const size_t oXLR = oXLO + (size_t)MP * KP1 * 2;          // xl|xr f16 [5000][8192]: 82 MB
  const size_t oBH  = oXLR + (size_t)N_NODES * N1 * 2;      // B bricks hi (4096 cols): 63.2 MB
  const size_t oBL  = oBH + (size_t)4096 * KP1 * 2;         // B bricks lo: 63.2 MB
  const size_t oS   = oBL + (size_t)4096 * KP1 * 2;
  const size_t oLATTR = alignup(oS);
  const size_t oDEG   = alignup(oLATTR + (size_t)N_NODES * 3 * 4);
  const size_t oEAF   = alignup(oDEG + (size_t)N_NODES * 4);
  const size_t oCNT   = alignup(oEAF + (size_t)EFULL * 3 * 4);
  const size_t oROW   = alignup(oCNT + (size_t)N_NODES * 4);
  const size_t oFILL  = alignup(oROW + (size_t)(N_NODES + 1) * 4);
  const size_t oELIST = alignup(oFILL + (size_t)N_NODES * 4);
  const size_t oLOGIT = alignup(oELIST + (size_t)EFULL * 4);
  const size_t oMB    = alignup(oLOGIT + (size_t)EFULL * 4 * 4);
  const size_t oDB    = alignup(oMB + (size_t)N_NODES * 4 * 4);
  const size_t oEND   = alignup(oDB + (size_t)N_NODES * 4 * 4);
  if (ws_size < oEND) return;

  // overlays (free by write time)
  const size_t oH1HI = oXHI;                            // H1 bricks: 41.9 MB (in 79)
  const size_t oH1LO = oXLO;
  const size_t oXLR2 = oXLR;                            // xl2|xr2 f16 [5000][2048]: 20.5 MB
  const size_t oH2HI = oXLR + 32ull * 1024 * 1024;      // H2 bricks: 10.5 MB
  const size_t oH2LO = oXLR + 48ull * 1024 * 1024;      // 10.5 MB
  const size_t oB2H  = oBH;                             // W2 bricks: 16.8 MB (in 63)
  const size_t oB2L  = oBL;
  const size_t oB3H  = oBH;                             // Wlin bricks: 0.26 MB
  const size_t oB3L  = oBH + 1ull * 1024 * 1024;

  unsigned short* XHI  = (unsigned short*)(ws + oXHI);
  unsigned short* XLO  = (unsigned short*)(ws + oXLO);
  f16*            XLR  = (f16*)(ws + oXLR);
  unsigned short* BH   = (unsigned short*)(ws + oBH);
  unsigned short* BL   = (unsigned short*)(ws + oBL);
  float*          LATTR= (float*)(ws + oLATTR);
  float*          DEG  = (float*)(ws + oDEG);
  float*          EAF  = (float*)(ws + oEAF);
  int*            CNT  = (int*)(ws + oCNT);
  int*            ROWP = (int*)(ws + oROW);
  int*            FILLC= (int*)(ws + oFILL);
  int*            ELIST= (int*)(ws + oELIST);
  float*          LOGIT= (float*)(ws + oLOGIT);
  float*          MB   = (float*)(ws + oMB);
  float*          DB   = (float*)(ws + oDB);
  unsigned short* H1HI = (unsigned short*)(ws + oH1HI);
  unsigned short* H1LO = (unsigned short*)(ws + oH1LO);
  f16*            XLR2 = (f16*)(ws + oXLR2);
  unsigned short* H2HI = (unsigned short*)(ws + oH2HI);
  unsigned short* H2LO = (unsigned short*)(ws + oH2LO);
  unsigned short* B2H  = (unsigned short*)(ws + oB2H);
  unsigned short* B2L  = (unsigned short*)(ws + oB2L);
  unsigned short* B3H  = (unsigned short*)(ws + oB3H);
  unsigned short* B3L  = (unsigned short*)(ws + oB3L);

  hipMemsetAsync(ws + oDEG,   0, (size_t)N_NODES * 4, stream);
  hipMemsetAsync(ws + oLATTR, 0, (size_t)N_NODES * 3 * 4, stream);
  hipMemsetAsync(ws + oCNT,   0, (size_t)N_NODES * 4, stream);
  hipMemsetAsync(ws + oFILL,  0, (size_t)N_NODES * 4, stream);

  const int gE  = (E_EDGES + 255) / 256;
  const int gEF = (EFULL + 255) / 256;
  const int gN  = (N_NODES + 255) / 256;

  // ---- graph structure ----
  k_deg<<<gE, 256, 0, stream>>>(dstp, eattr, DEG, LATTR, E_EDGES);
  k_lattr_fin<<<gN, 256, 0, stream>>>(LATTR, DEG, N_NODES);
  k_eafull<<<gEF, 256, 0, stream>>>(eattr, LATTR, EAF, E_EDGES, N_NODES);
  k_count<<<gEF, 256, 0, stream>>>(dstp, CNT, E_EDGES, N_NODES);
  k_scan<<<1, 64, 0, stream>>>(CNT, ROWP, N_NODES);
  k_fill<<<gEF, 256, 0, stream>>>(dstp, ROWP, FILLC, ELIST, E_EDGES, N_NODES);

  // ---- layer 1: A bricks, then W1l half / W1r half ----
  k_split_x<<<MP * (KP1 / 8) / 256, 256, 0, stream>>>(x, XHI, XLO);

  k_split_w<<<dim3(KT1, HC1 / 32), 256, 0, stream>>>(W1l, BH, BL, F_IN, HC1, 0, KT1, 0);
  k_gemm_bb<1><<<(HC1 / 128) * (MP / 128), 256, 0, stream>>>(
      XHI, XLO, BH, BL, XLR, b1l, b1l, HC1, N_NODES, N1, KT1, HC1 / 128);

  k_split_w<<<dim3(KT1, HC1 / 32), 256, 0, stream>>>(W1r, BH, BL, F_IN, HC1, 0, KT1, 0);
  k_gemm_bb<1><<<(HC1 / 128) * (MP / 128), 256, 0, stream>>>(
      XHI, XLO, BH, BL, XLR + HC1, b1r, b1r, HC1, N_NODES, N1, KT1, HC1 / 128);

  // ---- layer 1 attention + aggregation ----
  k_logit<4, 16><<<EFULL, 256, 0, stream>>>(XLR, XLR + HC1, N1, EAF, W1e, att1, srcp, dstp, E_EDGES, LOGIT);
  k_stats<4><<<N_NODES, 64, 0, stream>>>(LOGIT, ROWP, ELIST, MB, DB);
  hipMemsetAsync(ws + oH1HI, 0, (size_t)MP * HC1 * 2, stream);
  hipMemsetAsync(ws + oH1LO, 0, (size_t)MP * HC1 * 2, stream);
  k_agg<4, 2, HC1 / 32><<<N_NODES, 256, 0, stream>>>(
      XLR, N1, ROWP, ELIST, srcp, LOGIT, MB, DB, bias1, H1HI, H1LO, E_EDGES);

  // ---- layer 2 ----
  k_split_w<<<dim3(HC1 / 32, HC2 / 32), 256, 0, stream>>>(W2l, B2H, B2L, HC1, HC2, 0, HC1 / 32, 0);
  k_split_w<<<dim3(HC1 / 32, HC2 / 32), 256, 0, stream>>>(W2r, B2H, B2L, HC1, HC2, 0, HC1 / 32, HC2);
  k_gemm_bb<1><<<(N2 / 128) * (MP / 128), 256, 0, stream>>>(
      H1HI, H1LO, B2H, B2L, XLR2, b2l, b2r, HC2, N_NODES, N2, HC1 / 32, N2 / 128);

  k_logit<1, 4><<<EFULL, 256, 0, stream>>>(XLR2, XLR2 + HC2, N2, EAF, W2e, att2, srcp, dstp, E_EDGES, LOGIT);
  k_stats<1><<<N_NODES, 64, 0, stream>>>(LOGIT, ROWP, ELIST, MB, DB);
  hipMemsetAsync(ws + oH2HI, 0, (size_t)MP * HC2 * 2, stream);
  hipMemsetAsync(ws + oH2LO, 0, (size_t)MP * HC2 * 2, stream);
  k_agg<1, 1, HC2 / 32><<<N_NODES, 256, 0, stream>>>(
      XLR2, N2, ROWP, ELIST, srcp, LOGIT, MB, DB, bias2, H2HI, H2LO, E_EDGES);

  // ---- final linear ----
  k_split_w<<<dim3(HC2 / 32, NOUT / 32), 256, 0, stream>>>(Wlin, B3H, B3L, HC2, NOUT, 0, HC2 / 32, 0);
  k_gemm_bb<0><<<(NOUT / 128) * (MP / 128), 256, 0, stream>>>(
      H2HI, H2LO, B3H, B3L, out, blin, blin, NOUT, N_NODES, NOUT, HC2 / 32, NOUT / 128);
}